// Round 8
// baseline (434.636 us; speedup 1.0000x reference)
//
#include <hip/hip_runtime.h>
#include <math.h>

constexpr int Bc = 2, Nseq = 1024, Dh = 512, Nh = 16, Dhead = 32;
constexpr float FACT = 0.08838834764831845f; // 0.5/sqrt(32)
constexpr float LOG2E = 1.4426950408889634f;

typedef __attribute__((ext_vector_type(8))) __bf16 bf16x8;
typedef __attribute__((ext_vector_type(4))) float f32x4;

__device__ __forceinline__ short f2b(float x) {
    union { float f; unsigned u; } v; v.f = x;
    unsigned r = v.u + 0x7fffu + ((v.u >> 16) & 1u);
    return (short)(r >> 16);
}
__device__ __forceinline__ float b2f(short s) {
    union { unsigned u; float f; } v; v.u = ((unsigned)(unsigned short)s) << 16;
    return v.f;
}

// ---- shared 128x128-tile bf16 MFMA mainloop (A[M][K], B[N][K], both row-major bf16) ----
__device__ __forceinline__ void mfma_loop(const short* __restrict__ A, int lda,
                                          const short* __restrict__ B, int ldb,
                                          int K, short* __restrict__ smA,
                                          short* __restrict__ smB, f32x4 acc[4][4]) {
    const int tid = threadIdx.x;
    const int lane = tid & 63;
    const int w = tid >> 6;
    const int wr = (w >> 1) * 64, wc = (w & 1) * 64;
    const int lr = lane & 15;
    const int srow = tid >> 3;  // 0..31
    const int scol = tid & 7;   // 16B chunk 0..7
    for (int k0 = 0; k0 < K; k0 += 64) {
        bf16x8 ta[4], tb[4];
#pragma unroll
        for (int r = 0; r < 4; r++) {
            int row = r * 32 + srow;
            ta[r] = *(const bf16x8*)(A + (long)row * lda + k0 + scol * 8);
            tb[r] = *(const bf16x8*)(B + (long)row * ldb + k0 + scol * 8);
        }
        __syncthreads();
#pragma unroll
        for (int r = 0; r < 4; r++) {
            int row = r * 32 + srow;
            int c = scol ^ (row & 7);
            *(bf16x8*)(smA + row * 64 + c * 8) = ta[r];
            *(bf16x8*)(smB + row * 64 + c * 8) = tb[r];
        }
        __syncthreads();
#pragma unroll
        for (int h = 0; h < 2; h++) {
            int cb = h * 4 + (lane >> 4);
            bf16x8 af[4], bv[4];
#pragma unroll
            for (int i = 0; i < 4; i++) {
                int row = wr + i * 16 + lr;
                af[i] = *(const bf16x8*)(smA + row * 64 + ((cb ^ (row & 7)) << 3));
            }
#pragma unroll
            for (int j = 0; j < 4; j++) {
                int row = wc + j * 16 + lr;
                bv[j] = *(const bf16x8*)(smB + row * 64 + ((cb ^ (row & 7)) << 3));
            }
#pragma unroll
            for (int i = 0; i < 4; i++)
#pragma unroll
                for (int j = 0; j < 4; j++)
                    acc[i][j] = __builtin_amdgcn_mfma_f32_16x16x32_bf16(af[i], bv[j], acc[i][j], 0, 0, 0);
        }
    }
}

// flags: 1 = silu, 2 = output bf16
__global__ __launch_bounds__(256) void gemm_bf16(
    const short* __restrict__ A, int lda, long sAz,
    const short* __restrict__ B, int ldb, long sBz,
    void* __restrict__ C, int ldc, long sCz,
    const float* __restrict__ bias,
    const float* __restrict__ resid, int ldr, long sRz,
    int K, int flags)
{
    __shared__ short smA[128 * 64], smB[128 * 64];
    const long z = blockIdx.z;
    const short* Ab = A + z * sAz + (long)blockIdx.y * 128 * lda;
    const short* Bb = B + z * sBz + (long)blockIdx.x * 128 * ldb;
    f32x4 acc[4][4] = {};
    mfma_loop(Ab, lda, Bb, ldb, K, smA, smB, acc);
    const int tid = threadIdx.x, lane = tid & 63, w = tid >> 6;
    const int wr = (w >> 1) * 64, wc = (w & 1) * 64, lr = lane & 15, r0 = (lane >> 4) * 4;
    const int m0 = blockIdx.y * 128, n0 = blockIdx.x * 128;
    float* Cf = (float*)C; short* Cs = (short*)C;
    const float* rz = resid ? resid + z * sRz : nullptr;
#pragma unroll
    for (int i = 0; i < 4; i++)
#pragma unroll
        for (int j = 0; j < 4; j++) {
            int col = n0 + wc + j * 16 + lr;
            float bv = bias ? bias[col] : 0.f;
#pragma unroll
            for (int q = 0; q < 4; q++) {
                int row = m0 + wr + i * 16 + r0 + q;
                float c = acc[i][j][q] + bv;
                if (rz) c += rz[(long)row * ldr + col];
                if (flags & 1) c = c / (1.f + __expf(-c));
                long off = z * sCz + (long)row * ldc + col;
                if (flags & 2) Cs[off] = f2b(c); else Cf[off] = c;
            }
        }
}

// ---- fused flash attention v4: 256 threads (4 warps x 16 q-rows, QBLK=64),
// 2 blocks/CU (80KB LDS), warp-private bias/P regions (no barriers for them),
// 2 barriers/iter, prefetch spans the whole compute phase, log2-domain
// softmax with deferred rescale. ----
__global__ __launch_bounds__(256, 2) void flash_attn(
    const short* __restrict__ Hq, const short* __restrict__ Hk,
    const short* __restrict__ VaT, const float* __restrict__ rbf,
    const float* __restrict__ Dm, const float* __restrict__ maskadd,
    short* __restrict__ Hres, short* __restrict__ Vres, int ldq)
{
    __shared__ short smK[128 * 128];   // [kv m][d]   32KB
    __shared__ short smV[128 * 128];   // [d][kv m]   32KB
    __shared__ short smP[4 * 16 * 128]; // per-warp [16 q][128 kv] bias->P, 16KB
    const int bid = blockIdx.x;
    const int s = bid & 31, b = s >> 4, h = s & 15;  // slice fixed per XCD (bid%8)
    const int qt = bid >> 5;
    const int q0 = qt * 64;
    const int tid = threadIdx.x, lane = tid & 63, w = tid >> 6;
    const int lr = lane & 15, hi = lane >> 4, r0 = hi * 4;
    const int c16 = tid & 15, rS = tid >> 4;   // K/V staging: chunk, row base
    short* smPw = smP + w * 2048;

    // Q fragments (FACT*log2e pre-folded into Wq/bq)
    bf16x8 qf[4];
    {
        const short* qb = Hq + ((long)b * Nseq + q0 + w * 16 + lr) * ldq + h * 128 + hi * 8;
#pragma unroll
        for (int kk = 0; kk < 4; kk++) qf[kk] = *(const bf16x8*)(qb + kk * 32);
    }

    f32x4 oac[8] = {};
    float ml[4], ll[4];
#pragma unroll
    for (int q = 0; q < 4; q++) { ml[q] = -INFINITY; ll[q] = 0.f; }

    const short* Kg = Hk + (long)b * Nseq * ldq + h * 128;
    const short* Vg = VaT + (long)s * 128 * Nseq;
    const float* rbb = rbf + ((long)s * Nseq + q0 + w * 16) * Nseq;
    const float* Dbb = Dm + ((long)b * Nseq + q0 + w * 16) * Nseq;
    const float* mab = maskadd + b * Nseq;

    bf16x8 tk[8], tv[8];
    short4 hb[8];
    const int bl = lane;
    const int bcol = (bl & 31) * 4, brow2 = bl >> 5;
    auto LOADS = [&](int kt) {
#pragma unroll
        for (int r = 0; r < 8; r++) {
            int row = rS + r * 16;
            tk[r] = *(const bf16x8*)(Kg + (long)(kt * 128 + row) * ldq + c16 * 8);
            tv[r] = *(const bf16x8*)(Vg + (long)row * Nseq + kt * 128 + c16 * 8);
        }
        float4 mk = *(const float4*)(mab + kt * 128 + bcol);
#pragma unroll
        for (int it = 0; it < 8; it++) {
            int row = it * 2 + brow2;
            float4 rv = *(const float4*)(rbb + (long)row * Nseq + kt * 128 + bcol);
            float4 dv = *(const float4*)(Dbb + (long)row * Nseq + kt * 128 + bcol);
            short4 s4;
            s4.x = f2b((rv.x + dv.x + mk.x) * LOG2E);
            s4.y = f2b((rv.y + dv.y + mk.y) * LOG2E);
            s4.z = f2b((rv.z + dv.z + mk.z) * LOG2E);
            s4.w = f2b((rv.w + dv.w + mk.w) * LOG2E);
            hb[it] = s4;
        }
    };
    LOADS(0);

    for (int kt = 0; kt < 8; kt++) {
        __syncthreads();  // (1) prior iteration's LDS reads complete
#pragma unroll
        for (int r = 0; r < 8; r++) {
            int row = rS + r * 16;
            int pc = c16 ^ (row & 15);
            *(bf16x8*)(smK + row * 128 + pc * 8) = tk[r];
            *(bf16x8*)(smV + row * 128 + pc * 8) = tv[r];
        }
#pragma unroll
        for (int it = 0; it < 8; it++) {
            int row = it * 2 + brow2;
            int ch = bcol >> 3;
            *(short4*)(smPw + row * 128 + ((ch ^ (row & 7)) << 3) + (bcol & 7)) = hb[it];
        }
        __syncthreads();  // (2) K/V staged (bias is warp-local, ordered by lgkmcnt)
        if (kt < 7) LOADS(kt + 1);  // prefetch spans entire compute phase

        // S = Q @ K^T (log2 domain)
        f32x4 sac[8] = {};
#pragma unroll
        for (int kk = 0; kk < 4; kk++) {
            int cb = kk * 4 + hi;
            bf16x8 kv8[8];
#pragma unroll
            for (int j = 0; j < 8; j++) {
                int row = j * 16 + lr;
                kv8[j] = *(const bf16x8*)(smK + row * 128 + ((cb ^ (row & 15)) << 3));
            }
#pragma unroll
            for (int j = 0; j < 8; j++)
                sac[j] = __builtin_amdgcn_mfma_f32_16x16x32_bf16(qf[kk], kv8[j], sac[j], 0, 0, 0);
        }
        // bias add (warp-private LDS) + row max
        float tmax[4];
#pragma unroll
        for (int q = 0; q < 4; q++) tmax[q] = -INFINITY;
#pragma unroll
        for (int j = 0; j < 8; j++) {
            int col = j * 16 + lr;
            int ch = col >> 3, in8 = col & 7;
#pragma unroll
            for (int q = 0; q < 4; q++) {
                int row = r0 + q;
                float x = sac[j][q] + b2f(smPw[row * 128 + ((ch ^ (row & 7)) << 3) + in8]);
                sac[j][q] = x;
                tmax[q] = fmaxf(tmax[q], x);
            }
        }
#pragma unroll
        for (int st = 1; st < 16; st <<= 1)
#pragma unroll
            for (int q = 0; q < 4; q++) tmax[q] = fmaxf(tmax[q], __shfl_xor(tmax[q], st));
        // deferred rescale (T13): skip O-rescale when max growth <= 8 (log2 domain)
        float dm = -INFINITY;
#pragma unroll
        for (int q = 0; q < 4; q++) dm = fmaxf(dm, tmax[q] - ml[q]);
        if (!__all(dm <= 8.f)) {
#pragma unroll
            for (int q = 0; q < 4; q++) {
                float mn = fmaxf(ml[q], tmax[q]);
                float sc = exp2f(ml[q] - mn);
                ml[q] = mn;
                ll[q] *= sc;
#pragma unroll
                for (int j = 0; j < 8; j++) oac[j][q] *= sc;
            }
        }
        float rsum[4] = {0.f, 0.f, 0.f, 0.f};
#pragma unroll
        for (int j = 0; j < 8; j++)
#pragma unroll
            for (int q = 0; q < 4; q++) {
                float p = exp2f(sac[j][q] - ml[q]);
                sac[j][q] = p;
                rsum[q] += p;
            }
#pragma unroll
        for (int st = 1; st < 16; st <<= 1)
#pragma unroll
            for (int q = 0; q < 4; q++) rsum[q] += __shfl_xor(rsum[q], st);
#pragma unroll
        for (int q = 0; q < 4; q++) ll[q] += rsum[q];
        // P -> warp-private LDS (overwrites bias; same-warp ordering only)
#pragma unroll
        for (int j = 0; j < 8; j++) {
            int col = j * 16 + lr;
            int ch = col >> 3, in8 = col & 7;
#pragma unroll
            for (int q = 0; q < 4; q++) {
                int row = r0 + q;
                smPw[row * 128 + ((ch ^ (row & 7)) << 3) + in8] = f2b(sac[j][q]);
            }
        }
        // O += P @ V (A-frags from own warp's P region — no barrier needed)
#pragma unroll
        for (int kk = 0; kk < 4; kk++) {
            int cb = kk * 4 + hi;
            bf16x8 paf = *(const bf16x8*)(smPw + lr * 128 + ((cb ^ (lr & 7)) << 3));
            bf16x8 vv[8];
#pragma unroll
            for (int j = 0; j < 8; j++) {
                int row = j * 16 + lr;
                vv[j] = *(const bf16x8*)(smV + row * 128 + ((cb ^ (row & 15)) << 3));
            }
#pragma unroll
            for (int j = 0; j < 8; j++)
                oac[j] = __builtin_amdgcn_mfma_f32_16x16x32_bf16(paf, vv[j], oac[j], 0, 0, 0);
        }
    }
    // normalize + scatter
    float inv[4];
#pragma unroll
    for (int q = 0; q < 4; q++) inv[q] = 1.f / ll[q];
#pragma unroll
    for (int j = 0; j < 8; j++) {
        int d = j * 16 + lr;
#pragma unroll
        for (int q = 0; q < 4; q++) {
            int n = q0 + w * 16 + r0 + q;
            float o = oac[j][q] * inv[q];
            if (d < 32) Hres[((long)b * Nseq + n) * 512 + h * 32 + d] = f2b(o);
            else {
                int c3 = (d - 32) >> 5, dd = (d - 32) & 31;
                Vres[(((long)b * Nseq + n) * 3 + c3) * 512 + h * 32 + dd] = f2b(o);
            }
        }
    }
}

// ---- mask -> additive float (0 / -1e30) ----
__global__ __launch_bounds__(256) void maskprep(const int* __restrict__ mask,
                                                float* __restrict__ maskadd) {
    int i = blockIdx.x * 256 + threadIdx.x;
    maskadd[i] = mask[i] ? 0.f : -1e30f;
}

// ---- weight transpose + scale + f32->bf16: Wt[n][k] = W[k][n]*scale ----
__global__ __launch_bounds__(256) void tconv(const float* __restrict__ W,
                                             short* __restrict__ Wt, int K, int N,
                                             float scale) {
    __shared__ float t[32][33];
    int n0 = blockIdx.x * 32, k0 = blockIdx.y * 32;
    int tx = threadIdx.x & 31, ty = threadIdx.x >> 5;
#pragma unroll
    for (int r = 0; r < 4; r++) t[ty + r * 8][tx] = W[(long)(k0 + ty + r * 8) * N + n0 + tx];
    __syncthreads();
#pragma unroll
    for (int r = 0; r < 4; r++) Wt[(long)(n0 + ty + r * 8) * K + k0 + tx] = f2b(t[tx][ty + r * 8] * scale);
}

// ---- bqkv = [bq*FACT*log2e | bk | bvs] ----
__global__ __launch_bounds__(256) void bprep(const float* __restrict__ bq,
                                             const float* __restrict__ bk,
                                             const float* __restrict__ bvs,
                                             float* __restrict__ out) {
    int i = blockIdx.x * 256 + threadIdx.x;
    float v;
    if (i < 2048) v = bq[i] * (FACT * LOG2E);
    else if (i < 4096) v = bk[i - 2048];
    else v = bvs[i - 4096];
    out[i] = v;
}

// ---- f32 -> bf16 convert, 4/thread ----
__global__ __launch_bounds__(256) void convk(const float* __restrict__ in,
                                             short* __restrict__ out) {
    int i = blockIdx.x * 256 + threadIdx.x;
    float4 v = ((const float4*)in)[i];
    short4 s;
    s.x = f2b(v.x); s.y = f2b(v.y); s.z = f2b(v.z); s.w = f2b(v.w);
    ((short4*)out)[i] = s;
}

__device__ __forceinline__ void stv(float* p, float v) { *p = v; }
__device__ __forceinline__ void stv(short* p, float v) { *p = f2b(v); }

template <typename OT>
__global__ __launch_bounds__(256) void ln_kernel(const float* __restrict__ x,
                                                 const float* __restrict__ g,
                                                 const float* __restrict__ b,
                                                 OT* __restrict__ y) {
    int row = blockIdx.x;
    const float* xr = x + (long)row * Dh;
    OT* yr = y + (long)row * Dh;
    int tid = threadIdx.x;
    float v0 = xr[tid], v1 = xr[tid + 256];
    __shared__ float red[256];
    red[tid] = v0 + v1;
    __syncthreads();
    for (int o = 128; o > 0; o >>= 1) { if (tid < o) red[tid] += red[tid + o]; __syncthreads(); }
    float mean = red[0] * (1.0f / Dh);
    __syncthreads();
    float d0 = v0 - mean, d1 = v1 - mean;
    red[tid] = d0 * d0 + d1 * d1;
    __syncthreads();
    for (int o = 128; o > 0; o >>= 1) { if (tid < o) red[tid] += red[tid + o]; __syncthreads(); }
    float rstd = rsqrtf(red[0] * (1.0f / Dh) + 1e-5f);
    stv(&yr[tid], d0 * rstd * g[tid] + b[tid]);
    stv(&yr[tid + 256], d1 * rstd * g[tid + 256] + b[tid + 256]);
}

// ---- Vattn_t[slice][d][m] gather (bf16); Hv has row stride ldh ----
__global__ __launch_bounds__(256) void vattn_t(const short* __restrict__ Hv, int ldh,
                                               const short* __restrict__ Vv,
                                               short* __restrict__ VaT) {
    int idx = blockIdx.x * 256 + threadIdx.x;
    int m = idx & 1023, d = (idx >> 10) & 127;
    int s = idx >> 17; int b = s >> 4, h = s & 15;
    short val;
    if (d < 32) val = Hv[((long)b * Nseq + m) * ldh + h * 32 + d];
    else {
        int c3 = (d - 32) >> 5, dd = (d - 32) & 31;
        val = Vv[(((long)b * Nseq + m) * 3 + c3) * 512 + h * 32 + dd];
    }
    VaT[idx] = val;
}

// ---- scaler = [Hn2 | ||V1||] as bf16 ----
__global__ __launch_bounds__(256) void scaler_k(const float* __restrict__ Hn2,
                                                const float* __restrict__ Vp,
                                                short* __restrict__ scaler) {
    int idx = blockIdx.x * 256 + threadIdx.x; // B*N*512
    int j = idx & 511;
    int row = idx >> 9;
    scaler[(long)row * 1024 + j] = f2b(Hn2[idx]);
    float ss = 0.f;
#pragma unroll
    for (int c = 0; c < 3; c++) {
        float v = Vp[((long)row * 3 + c) * 1024 + j];
        ss += v * v;
    }
    scaler[(long)row * 1024 + 512 + j] = f2b(sqrtf(ss));
}

// ---- final: H += s[:512]; V += s[512:] * V2 ----
__global__ __launch_bounds__(256) void final_k(float* __restrict__ outH,
                                               float* __restrict__ outV,
                                               const float* __restrict__ s,
                                               const float* __restrict__ Vp) {
    int idx = blockIdx.x * 256 + threadIdx.x; // B*N*512
    int j = idx & 511;
    int row = idx >> 9;
    outH[idx] += s[(long)row * 1024 + j];
    float vu = s[(long)row * 1024 + 512 + j];
#pragma unroll
    for (int c = 0; c < 3; c++) {
        long vi = ((long)row * 3 + c) * Dh + j;
        outV[vi] += vu * Vp[((long)row * 3 + c) * 1024 + 512 + j];
    }
}

extern "C" void kernel_launch(void* const* d_in, const int* in_sizes, int n_in,
                              void* d_out, int out_size, void* d_ws, size_t ws_size,
                              hipStream_t stream) {
    const float* H    = (const float*)d_in[0];
    const float* V    = (const float*)d_in[1];
    const float* Dm   = (const float*)d_in[2];
    const float* rbf  = (const float*)d_in[3];
    const int*   mask = (const int*)d_in[4];
    const float* Wq   = (const float*)d_in[5];
    const float* bq   = (const float*)d_in[6];
    const float* Wk   = (const float*)d_in[7];
    const float* bk   = (const float*)d_in[8];
    const float* Wvs  = (const float*)d_in[9];
    const float* bvs  = (const float*)d_in[10];
    const float* Wvv  = (const float*)d_in[11];
    const float* Wo   = (const float*)d_in[12];
    const float* bo   = (const float*)d_in[13];
    const float* Wvo  = (const float*)d_in[14];
    const float* ln1g = (const float*)d_in[15];
    const float* ln1b = (const float*)d_in[16];
    const float* Wlv  = (const float*)d_in[17];
    const float* W1   = (const float*)d_in[18];
    const float* b1   = (const float*)d_in[19];
    const float* W2   = (const float*)d_in[20];
    const float* b2   = (const float*)d_in[21];
    const float* ln2g = (const float*)d_in[22];
    const float* ln2b = (const float*)d_in[23];

    char* wsb = (char*)d_ws;
    auto KB = [&](long kb) { return (void*)(wsb + kb * 1024l); };
    // weights (persistent through the call)
    short* WqkvT = (short*)KB(0);      // [4608][512] bf16, 4.5MB
    short* WvvT  = (short*)KB(4608);
    short* WoT   = (short*)KB(5120);
    short* WvoT  = (short*)KB(5632);
    short* WlvT  = (short*)KB(6144);
    short* W1T   = (short*)KB(7168);
    short* W2T   = (short*)KB(11264);  // ..15360
    float* bqkv  = (float*)KB(15360);  // 18KB
    // phase 1
    short* Hqkv = (short*)KB(15384);   // [2048][4608] bf16, 18MB ..33816
    short* VvR  = (short*)KB(33816);   // 6MB ..39960
    short* VaT  = (short*)KB(39960);   // 8MB ..48152
    short* Hn   = (short*)KB(48152);   // 2MB ..50200
    short* Vbf  = (short*)KB(50200);   // 6MB ..56344
    short* Hres = (short*)KB(56344);   // 2MB ..58392
    short* Vres = (short*)KB(58392);   // 6MB ..64536
    float* maskadd = (float*)KB(64536);
    // phase 2 (reuses dead phase-1 regions)
    float* Hn2    = (float*)KB(0);      // 4MB (WqkvT dead)
    short* Vbf2   = (short*)KB(15384);  // 6MB (Hqkv dead)
    float* Vp     = (float*)KB(21528);  // 24MB ..45576
    short* scaler = (short*)KB(46104);  // 4MB
    short* t1     = (short*)KB(50200);  // 8MB (Vbf/Hres dead)
    float* sbuf   = (float*)KB(58392);  // 8MB (Vres dead after Wvo proj)

    float* outH = (float*)d_out;
    float* outV = outH + (size_t)Bc * Nseq * Dh;

    // weight transposes + converts (FACT*log2e folded into Wq/bq)
    tconv<<<dim3(64, 16), 256, 0, stream>>>(Wq, WqkvT, 512, 2048, FACT * LOG2E);
    tconv<<<dim3(64, 16), 256, 0, stream>>>(Wk, WqkvT + 2048 * 512, 512, 2048, 1.f);
    tconv<<<dim3(16, 16), 256, 0, stream>>>(Wvs, WqkvT + 4096 * 512, 512, 512, 1.f);
    tconv<<<dim3(16, 16), 256, 0, stream>>>(Wvv, WvvT, 512, 512, 1.f);
    tconv<<<dim3(16, 16), 256, 0, stream>>>(Wo, WoT, 512, 512, 1.f);
    tconv<<<dim3(16, 16), 256, 0, stream>>>(Wvo, WvoT, 512, 512, 1.f);
    tconv<<<dim3(32, 16), 256, 0, stream>>>(Wlv, WlvT, 512, 1024, 1.f);
    tconv<<<dim3(64, 32), 256, 0, stream>>>(W1, W1T, 1024, 2048, 1.f);
    tconv<<<dim3(32, 64), 256, 0, stream>>>(W2, W2T, 2048, 1024, 1.f);
    bprep<<<18, 256, 0, stream>>>(bq, bk, bvs, bqkv);
    convk<<<3072, 256, 0, stream>>>(V, Vbf);
    maskprep<<<8, 256, 0, stream>>>(mask, maskadd);

    // LN1 -> bf16
    ln_kernel<short><<<2048, 256, 0, stream>>>(H, ln1g, ln1b, Hn);
    // merged QKV projection (bf16 out): Hqkv[2048][4608]
    gemm_bf16<<<dim3(36, 16, 1), 256, 0, stream>>>(Hn, 512, 0, WqkvT, 512, 0, Hqkv, 4608, 0,
                                                   bqkv, nullptr, 0, 0, 512, 2);
    gemm_bf16<<<dim3(4, 48, 1), 256, 0, stream>>>(Vbf, 512, 0, WvvT, 512, 0, VvR, 512, 0,
                                                  nullptr, nullptr, 0, 0, 512, 2);
    vattn_t<<<16384, 256, 0, stream>>>(Hqkv + 4096, 4608, VvR, VaT);

    // fused flash attention: 512 blocks x 256 threads, QBLK=64
    flash_attn<<<dim3(512), 256, 0, stream>>>(Hqkv, Hqkv + 2048, VaT, rbf, Dm, maskadd,
                                              Hres, Vres, 4608);

    // output projections with residuals (f32 into d_out)
    gemm_bf16<<<dim3(4, 16, 1), 256, 0, stream>>>(Hres, 512, 0, WoT, 512, 0, outH, 512, 0,
                                                  bo, H, 512, 0, 512, 0);
    gemm_bf16<<<dim3(4, 48, 1), 256, 0, stream>>>(Vres, 512, 0, WvoT, 512, 0, outV, 512, 0,
                                                  nullptr, V, 512, 0, 512, 0);
    convk<<<3072, 256, 0, stream>>>(outV, Vbf2);
    ln_kernel<float><<<2048, 256, 0, stream>>>(outH, ln2g, ln2b, Hn2);
    gemm_bf16<<<dim3(8, 48, 1), 256, 0, stream>>>(Vbf2, 512, 0, WlvT, 512, 0, Vp, 1024, 0,
                                                  nullptr, nullptr, 0, 0, 512, 0);
    scaler_k<<<4096, 256, 0, stream>>>(Hn2, Vp, scaler);
    gemm_bf16<<<dim3(16, 16, 1), 256, 0, stream>>>(scaler, 1024, 0, W1T, 1024, 0, t1, 2048, 0,
                                                   b1, nullptr, 0, 0, 1024, 3);
    gemm_bf16<<<dim3(8, 16, 1), 256, 0, stream>>>(t1, 2048, 0, W2T, 2048, 0, sbuf, 1024, 0,
                                                  b2, nullptr, 0, 0, 2048, 0);
    final_k<<<4096, 256, 0, stream>>>(outH, outV, sbuf, Vp);
}

// Round 9
// 333.497 us; speedup vs baseline: 1.3033x; 1.3033x over previous
//
#include <hip/hip_runtime.h>
#include <math.h>

constexpr int Bc = 2, Nseq = 1024, Dh = 512, Nh = 16, Dhead = 32;
constexpr float FACT = 0.08838834764831845f; // 0.5/sqrt(32)
constexpr float LOG2E = 1.4426950408889634f;

typedef __attribute__((ext_vector_type(8))) __bf16 bf16x8;
typedef __attribute__((ext_vector_type(4))) float f32x4;

__device__ __forceinline__ short f2b(float x) {
    union { float f; unsigned u; } v; v.f = x;
    unsigned r = v.u + 0x7fffu + ((v.u >> 16) & 1u);
    return (short)(r >> 16);
}
__device__ __forceinline__ float b2f(short s) {
    union { unsigned u; float f; } v; v.u = ((unsigned)(unsigned short)s) << 16;
    return v.f;
}

// ---- shared 128x128-tile bf16 MFMA mainloop (A[M][K], B[N][K], both row-major bf16) ----
__device__ __forceinline__ void mfma_loop(const short* __restrict__ A, int lda,
                                          const short* __restrict__ B, int ldb,
                                          int K, short* __restrict__ smA,
                                          short* __restrict__ smB, f32x4 acc[4][4]) {
    const int tid = threadIdx.x;
    const int lane = tid & 63;
    const int w = tid >> 6;
    const int wr = (w >> 1) * 64, wc = (w & 1) * 64;
    const int lr = lane & 15;
    const int srow = tid >> 3;  // 0..31
    const int scol = tid & 7;   // 16B chunk 0..7
    for (int k0 = 0; k0 < K; k0 += 64) {
        bf16x8 ta[4], tb[4];
#pragma unroll
        for (int r = 0; r < 4; r++) {
            int row = r * 32 + srow;
            ta[r] = *(const bf16x8*)(A + (long)row * lda + k0 + scol * 8);
            tb[r] = *(const bf16x8*)(B + (long)row * ldb + k0 + scol * 8);
        }
        __syncthreads();
#pragma unroll
        for (int r = 0; r < 4; r++) {
            int row = r * 32 + srow;
            int c = scol ^ (row & 7);
            *(bf16x8*)(smA + row * 64 + c * 8) = ta[r];
            *(bf16x8*)(smB + row * 64 + c * 8) = tb[r];
        }
        __syncthreads();
#pragma unroll
        for (int h = 0; h < 2; h++) {
            int cb = h * 4 + (lane >> 4);
            bf16x8 af[4], bv[4];
#pragma unroll
            for (int i = 0; i < 4; i++) {
                int row = wr + i * 16 + lr;
                af[i] = *(const bf16x8*)(smA + row * 64 + ((cb ^ (row & 7)) << 3));
            }
#pragma unroll
            for (int j = 0; j < 4; j++) {
                int row = wc + j * 16 + lr;
                bv[j] = *(const bf16x8*)(smB + row * 64 + ((cb ^ (row & 7)) << 3));
            }
#pragma unroll
            for (int i = 0; i < 4; i++)
#pragma unroll
                for (int j = 0; j < 4; j++)
                    acc[i][j] = __builtin_amdgcn_mfma_f32_16x16x32_bf16(af[i], bv[j], acc[i][j], 0, 0, 0);
        }
    }
}

// flags: 1 = silu, 2 = output bf16
__global__ __launch_bounds__(256) void gemm_bf16(
    const short* __restrict__ A, int lda, long sAz,
    const short* __restrict__ B, int ldb, long sBz,
    void* __restrict__ C, int ldc, long sCz,
    const float* __restrict__ bias,
    const float* __restrict__ resid, int ldr, long sRz,
    int K, int flags)
{
    __shared__ short smA[128 * 64], smB[128 * 64];
    const long z = blockIdx.z;
    const short* Ab = A + z * sAz + (long)blockIdx.y * 128 * lda;
    const short* Bb = B + z * sBz + (long)blockIdx.x * 128 * ldb;
    f32x4 acc[4][4] = {};
    mfma_loop(Ab, lda, Bb, ldb, K, smA, smB, acc);
    const int tid = threadIdx.x, lane = tid & 63, w = tid >> 6;
    const int wr = (w >> 1) * 64, wc = (w & 1) * 64, lr = lane & 15, r0 = (lane >> 4) * 4;
    const int m0 = blockIdx.y * 128, n0 = blockIdx.x * 128;
    float* Cf = (float*)C; short* Cs = (short*)C;
    const float* rz = resid ? resid + z * sRz : nullptr;
#pragma unroll
    for (int i = 0; i < 4; i++)
#pragma unroll
        for (int j = 0; j < 4; j++) {
            int col = n0 + wc + j * 16 + lr;
            float bv = bias ? bias[col] : 0.f;
#pragma unroll
            for (int q = 0; q < 4; q++) {
                int row = m0 + wr + i * 16 + r0 + q;
                float c = acc[i][j][q] + bv;
                if (rz) c += rz[(long)row * ldr + col];
                if (flags & 1) c = c / (1.f + __expf(-c));
                long off = z * sCz + (long)row * ldc + col;
                if (flags & 2) Cs[off] = f2b(c); else Cf[off] = c;
            }
        }
}

// ---- fused flash attention v5: 256 threads (4 warps x 16 q-rows, QBLK=64),
// 2 blocks/CU (80KB LDS), warp-private bias/P (2 barriers/iter), NO register
// prefetch (spill-free: live regs ~110 < 128), XCD-aware mapping so a slice's
// 16 q-blocks share K/V via one XCD's L2, log2 softmax + deferred rescale. ----
__global__ __launch_bounds__(256, 2) void flash_attn(
    const short* __restrict__ Hq, const short* __restrict__ Hk,
    const short* __restrict__ VaT, const float* __restrict__ rbf,
    const float* __restrict__ Dm, const float* __restrict__ maskadd,
    short* __restrict__ Hres, short* __restrict__ Vres, int ldq)
{
    __shared__ short smK[128 * 128];    // [kv m][d]   32KB
    __shared__ short smV[128 * 128];    // [d][kv m]   32KB
    __shared__ short smP[4 * 16 * 128]; // per-warp bias->P, 16KB
    // XCD-aware: all 16 q-tiles of a slice land on one XCD (round-robin bid%8)
    const int xcd = blockIdx.x & 7, idx = blockIdx.x >> 3;
    const int s = (idx >> 4) * 8 + xcd;  // 0..31
    const int qt = idx & 15;
    const int b = s >> 4, h = s & 15;
    const int q0 = qt * 64;
    const int tid = threadIdx.x, lane = tid & 63, w = tid >> 6;
    const int lr = lane & 15, hi = lane >> 4, r0 = hi * 4;
    const int c16 = tid & 15, rS = tid >> 4;   // staging: chunk 0..15, row base 0..15
    short* smPw = smP + w * 2048;

    // Q fragments (FACT*log2e pre-folded into Wq/bq)
    bf16x8 qf[4];
    {
        const short* qb = Hq + ((long)b * Nseq + q0 + w * 16 + lr) * ldq + h * 128 + hi * 8;
#pragma unroll
        for (int kk = 0; kk < 4; kk++) qf[kk] = *(const bf16x8*)(qb + kk * 32);
    }

    f32x4 oac[8] = {};
    float ml[4], ll[4];
#pragma unroll
    for (int q = 0; q < 4; q++) { ml[q] = -INFINITY; ll[q] = 0.f; }

    const short* Kg = Hk + (long)b * Nseq * ldq + h * 128;
    const short* Vg = VaT + (long)s * 128 * Nseq;
    const float* rbb = rbf + ((long)s * Nseq + q0 + w * 16) * Nseq;
    const float* Dbb = Dm + ((long)b * Nseq + q0 + w * 16) * Nseq;
    const float* mab = maskadd + b * Nseq;
    const int bcol = (lane & 31) * 4, brow2 = lane >> 5;

    for (int kt = 0; kt < 8; kt++) {
        __syncthreads();  // (1) prior iteration's LDS reads complete
        {
            bf16x8 t8[8];
#pragma unroll
            for (int r = 0; r < 8; r++)
                t8[r] = *(const bf16x8*)(Kg + (long)(kt * 128 + rS + r * 16) * ldq + c16 * 8);
#pragma unroll
            for (int r = 0; r < 8; r++) {
                int row = rS + r * 16;
                *(bf16x8*)(smK + row * 128 + (c16 ^ (row & 15)) * 8) = t8[r];
            }
#pragma unroll
            for (int r = 0; r < 8; r++)
                t8[r] = *(const bf16x8*)(Vg + (long)(rS + r * 16) * Nseq + kt * 128 + c16 * 8);
#pragma unroll
            for (int r = 0; r < 8; r++) {
                int row = rS + r * 16;
                *(bf16x8*)(smV + row * 128 + (c16 ^ (row & 15)) * 8) = t8[r];
            }
        }
        {
            short4 hb[8];
            float4 mk = *(const float4*)(mab + kt * 128 + bcol);
#pragma unroll
            for (int it = 0; it < 8; it++) {
                int row = it * 2 + brow2;
                float4 rv = *(const float4*)(rbb + (long)row * Nseq + kt * 128 + bcol);
                float4 dv = *(const float4*)(Dbb + (long)row * Nseq + kt * 128 + bcol);
                hb[it].x = f2b((rv.x + dv.x + mk.x) * LOG2E);
                hb[it].y = f2b((rv.y + dv.y + mk.y) * LOG2E);
                hb[it].z = f2b((rv.z + dv.z + mk.z) * LOG2E);
                hb[it].w = f2b((rv.w + dv.w + mk.w) * LOG2E);
            }
            int ch = bcol >> 3;
#pragma unroll
            for (int it = 0; it < 8; it++) {
                int row = it * 2 + brow2;
                *(short4*)(smPw + row * 128 + ((ch ^ (row & 7)) << 3) + (bcol & 7)) = hb[it];
            }
        }
        __syncthreads();  // (2) K/V/bias staged

        // S = Q @ K^T (log2 domain)
        f32x4 sac[8] = {};
#pragma unroll
        for (int kk = 0; kk < 4; kk++) {
            int cb = kk * 4 + hi;
            bf16x8 kv8[8];
#pragma unroll
            for (int j = 0; j < 8; j++) {
                int row = j * 16 + lr;
                kv8[j] = *(const bf16x8*)(smK + row * 128 + ((cb ^ (row & 15)) << 3));
            }
#pragma unroll
            for (int j = 0; j < 8; j++)
                sac[j] = __builtin_amdgcn_mfma_f32_16x16x32_bf16(qf[kk], kv8[j], sac[j], 0, 0, 0);
        }
        // bias add (warp-private LDS) + row max
        float tmax[4];
#pragma unroll
        for (int q = 0; q < 4; q++) tmax[q] = -INFINITY;
#pragma unroll
        for (int j = 0; j < 8; j++) {
            int col = j * 16 + lr;
            int ch = col >> 3, in8 = col & 7;
#pragma unroll
            for (int q = 0; q < 4; q++) {
                int row = r0 + q;
                float x = sac[j][q] + b2f(smPw[row * 128 + ((ch ^ (row & 7)) << 3) + in8]);
                sac[j][q] = x;
                tmax[q] = fmaxf(tmax[q], x);
            }
        }
#pragma unroll
        for (int st = 1; st < 16; st <<= 1)
#pragma unroll
            for (int q = 0; q < 4; q++) tmax[q] = fmaxf(tmax[q], __shfl_xor(tmax[q], st));
        // deferred rescale (T13)
        float dm = -INFINITY;
#pragma unroll
        for (int q = 0; q < 4; q++) dm = fmaxf(dm, tmax[q] - ml[q]);
        if (!__all(dm <= 8.f)) {
#pragma unroll
            for (int q = 0; q < 4; q++) {
                float mn = fmaxf(ml[q], tmax[q]);
                float sc = exp2f(ml[q] - mn);
                ml[q] = mn;
                ll[q] *= sc;
#pragma unroll
                for (int j = 0; j < 8; j++) oac[j][q] *= sc;
            }
        }
        float rsum[4] = {0.f, 0.f, 0.f, 0.f};
#pragma unroll
        for (int j = 0; j < 8; j++)
#pragma unroll
            for (int q = 0; q < 4; q++) {
                float p = exp2f(sac[j][q] - ml[q]);
                sac[j][q] = p;
                rsum[q] += p;
            }
#pragma unroll
        for (int st = 1; st < 16; st <<= 1)
#pragma unroll
            for (int q = 0; q < 4; q++) rsum[q] += __shfl_xor(rsum[q], st);
#pragma unroll
        for (int q = 0; q < 4; q++) ll[q] += rsum[q];
        // P -> warp-private LDS (same-warp ordering via lgkmcnt; no barrier)
#pragma unroll
        for (int j = 0; j < 8; j++) {
            int col = j * 16 + lr;
            int ch = col >> 3, in8 = col & 7;
#pragma unroll
            for (int q = 0; q < 4; q++) {
                int row = r0 + q;
                smPw[row * 128 + ((ch ^ (row & 7)) << 3) + in8] = f2b(sac[j][q]);
            }
        }
        // O += P @ V
#pragma unroll
        for (int kk = 0; kk < 4; kk++) {
            int cb = kk * 4 + hi;
            bf16x8 paf = *(const bf16x8*)(smPw + lr * 128 + ((cb ^ (lr & 7)) << 3));
            bf16x8 vv[8];
#pragma unroll
            for (int j = 0; j < 8; j++) {
                int row = j * 16 + lr;
                vv[j] = *(const bf16x8*)(smV + row * 128 + ((cb ^ (row & 15)) << 3));
            }
#pragma unroll
            for (int j = 0; j < 8; j++)
                oac[j] = __builtin_amdgcn_mfma_f32_16x16x32_bf16(paf, vv[j], oac[j], 0, 0, 0);
        }
    }
    // normalize + scatter
    float inv[4];
#pragma unroll
    for (int q = 0; q < 4; q++) inv[q] = 1.f / ll[q];
#pragma unroll
    for (int j = 0; j < 8; j++) {
        int d = j * 16 + lr;
#pragma unroll
        for (int q = 0; q < 4; q++) {
            int n = q0 + w * 16 + r0 + q;
            float o = oac[j][q] * inv[q];
            if (d < 32) Hres[((long)b * Nseq + n) * 512 + h * 32 + d] = f2b(o);
            else {
                int c3 = (d - 32) >> 5, dd = (d - 32) & 31;
                Vres[(((long)b * Nseq + n) * 3 + c3) * 512 + h * 32 + dd] = f2b(o);
            }
        }
    }
}

// ---- mask -> additive float (0 / -1e30) ----
__global__ __launch_bounds__(256) void maskprep(const int* __restrict__ mask,
                                                float* __restrict__ maskadd) {
    int i = blockIdx.x * 256 + threadIdx.x;
    maskadd[i] = mask[i] ? 0.f : -1e30f;
}

// ---- weight transpose + scale + f32->bf16: Wt[n][k] = W[k][n]*scale ----
__global__ __launch_bounds__(256) void tconv(const float* __restrict__ W,
                                             short* __restrict__ Wt, int K, int N,
                                             float scale) {
    __shared__ float t[32][33];
    int n0 = blockIdx.x * 32, k0 = blockIdx.y * 32;
    int tx = threadIdx.x & 31, ty = threadIdx.x >> 5;
#pragma unroll
    for (int r = 0; r < 4; r++) t[ty + r * 8][tx] = W[(long)(k0 + ty + r * 8) * N + n0 + tx];
    __syncthreads();
#pragma unroll
    for (int r = 0; r < 4; r++) Wt[(long)(n0 + ty + r * 8) * K + k0 + tx] = f2b(t[tx][ty + r * 8] * scale);
}

// ---- bqkv = [bq*FACT*log2e | bk | bvs] ----
__global__ __launch_bounds__(256) void bprep(const float* __restrict__ bq,
                                             const float* __restrict__ bk,
                                             const float* __restrict__ bvs,
                                             float* __restrict__ out) {
    int i = blockIdx.x * 256 + threadIdx.x;
    float v;
    if (i < 2048) v = bq[i] * (FACT * LOG2E);
    else if (i < 4096) v = bk[i - 2048];
    else v = bvs[i - 4096];
    out[i] = v;
}

// ---- f32 -> bf16 convert, 4/thread ----
__global__ __launch_bounds__(256) void convk(const float* __restrict__ in,
                                             short* __restrict__ out) {
    int i = blockIdx.x * 256 + threadIdx.x;
    float4 v = ((const float4*)in)[i];
    short4 s;
    s.x = f2b(v.x); s.y = f2b(v.y); s.z = f2b(v.z); s.w = f2b(v.w);
    ((short4*)out)[i] = s;
}

__device__ __forceinline__ void stv(float* p, float v) { *p = v; }
__device__ __forceinline__ void stv(short* p, float v) { *p = f2b(v); }

template <typename OT>
__global__ __launch_bounds__(256) void ln_kernel(const float* __restrict__ x,
                                                 const float* __restrict__ g,
                                                 const float* __restrict__ b,
                                                 OT* __restrict__ y) {
    int row = blockIdx.x;
    const float* xr = x + (long)row * Dh;
    OT* yr = y + (long)row * Dh;
    int tid = threadIdx.x;
    float v0 = xr[tid], v1 = xr[tid + 256];
    __shared__ float red[256];
    red[tid] = v0 + v1;
    __syncthreads();
    for (int o = 128; o > 0; o >>= 1) { if (tid < o) red[tid] += red[tid + o]; __syncthreads(); }
    float mean = red[0] * (1.0f / Dh);
    __syncthreads();
    float d0 = v0 - mean, d1 = v1 - mean;
    red[tid] = d0 * d0 + d1 * d1;
    __syncthreads();
    for (int o = 128; o > 0; o >>= 1) { if (tid < o) red[tid] += red[tid + o]; __syncthreads(); }
    float rstd = rsqrtf(red[0] * (1.0f / Dh) + 1e-5f);
    stv(&yr[tid], d0 * rstd * g[tid] + b[tid]);
    stv(&yr[tid + 256], d1 * rstd * g[tid + 256] + b[tid + 256]);
}

// ---- Vattn_t[slice][d][m] gather (bf16); Hv has row stride ldh ----
__global__ __launch_bounds__(256) void vattn_t(const short* __restrict__ Hv, int ldh,
                                               const short* __restrict__ Vv,
                                               short* __restrict__ VaT) {
    int idx = blockIdx.x * 256 + threadIdx.x;
    int m = idx & 1023, d = (idx >> 10) & 127;
    int s = idx >> 17; int b = s >> 4, h = s & 15;
    short val;
    if (d < 32) val = Hv[((long)b * Nseq + m) * ldh + h * 32 + d];
    else {
        int c3 = (d - 32) >> 5, dd = (d - 32) & 31;
        val = Vv[(((long)b * Nseq + m) * 3 + c3) * 512 + h * 32 + dd];
    }
    VaT[idx] = val;
}

// ---- scaler = [Hn2 | ||V1||] as bf16 ----
__global__ __launch_bounds__(256) void scaler_k(const float* __restrict__ Hn2,
                                                const float* __restrict__ Vp,
                                                short* __restrict__ scaler) {
    int idx = blockIdx.x * 256 + threadIdx.x; // B*N*512
    int j = idx & 511;
    int row = idx >> 9;
    scaler[(long)row * 1024 + j] = f2b(Hn2[idx]);
    float ss = 0.f;
#pragma unroll
    for (int c = 0; c < 3; c++) {
        float v = Vp[((long)row * 3 + c) * 1024 + j];
        ss += v * v;
    }
    scaler[(long)row * 1024 + 512 + j] = f2b(sqrtf(ss));
}

// ---- final: H += s[:512]; V += s[512:] * V2 ----
__global__ __launch_bounds__(256) void final_k(float* __restrict__ outH,
                                               float* __restrict__ outV,
                                               const float* __restrict__ s,
                                               const float* __restrict__ Vp) {
    int idx = blockIdx.x * 256 + threadIdx.x; // B*N*512
    int j = idx & 511;
    int row = idx >> 9;
    outH[idx] += s[(long)row * 1024 + j];
    float vu = s[(long)row * 1024 + 512 + j];
#pragma unroll
    for (int c = 0; c < 3; c++) {
        long vi = ((long)row * 3 + c) * Dh + j;
        outV[vi] += vu * Vp[((long)row * 3 + c) * 1024 + 512 + j];
    }
}

extern "C" void kernel_launch(void* const* d_in, const int* in_sizes, int n_in,
                              void* d_out, int out_size, void* d_ws, size_t ws_size,
                              hipStream_t stream) {
    const float* H    = (const float*)d_in[0];
    const float* V    = (const float*)d_in[1];
    const float* Dm   = (const float*)d_in[2];
    const float* rbf  = (const float*)d_in[3];
    const int*   mask = (const int*)d_in[4];
    const float* Wq   = (const float*)d_in[5];
    const float* bq   = (const float*)d_in[6];
    const float* Wk   = (const float*)d_in[7];
    const float* bk   = (const float*)d_in[8];
    const float* Wvs  = (const float*)d_in[9];
    const float* bvs  = (const float*)d_in[10];
    const float* Wvv  = (const float*)d_in[11];
    const float* Wo   = (const float*)d_in[12];
    const float* bo   = (const float*)d_in[13];
    const float* Wvo  = (const float*)d_in[14];
    const float* ln1g = (const float*)d_in[15];
    const float* ln1b = (const float*)d_in[16];
    const float* Wlv  = (const float*)d_in[17];
    const float* W1   = (const float*)d_in[18];
    const float* b1   = (const float*)d_in[19];
    const float* W2   = (const float*)d_in[20];
    const float* b2   = (const float*)d_in[21];
    const float* ln2g = (const float*)d_in[22];
    const float* ln2b = (const float*)d_in[23];

    char* wsb = (char*)d_ws;
    auto KB = [&](long kb) { return (void*)(wsb + kb * 1024l); };
    // weights (persistent through the call)
    short* WqkvT = (short*)KB(0);      // [4608][512] bf16, 4.5MB
    short* WvvT  = (short*)KB(4608);
    short* WoT   = (short*)KB(5120);
    short* WvoT  = (short*)KB(5632);
    short* WlvT  = (short*)KB(6144);
    short* W1T   = (short*)KB(7168);
    short* W2T   = (short*)KB(11264);  // ..15360
    float* bqkv  = (float*)KB(15360);  // 18KB
    // phase 1
    short* Hqkv = (short*)KB(15384);   // [2048][4608] bf16, 18MB ..33816
    short* VvR  = (short*)KB(33816);   // 6MB ..39960
    short* VaT  = (short*)KB(39960);   // 8MB ..48152
    short* Hn   = (short*)KB(48152);   // 2MB ..50200
    short* Vbf  = (short*)KB(50200);   // 6MB ..56344
    short* Hres = (short*)KB(56344);   // 2MB ..58392
    short* Vres = (short*)KB(58392);   // 6MB ..64536
    float* maskadd = (float*)KB(64536);
    // phase 2 (reuses dead phase-1 regions)
    float* Hn2    = (float*)KB(0);      // 4MB (WqkvT dead)
    short* Vbf2   = (short*)KB(15384);  // 6MB (Hqkv dead)
    float* Vp     = (float*)KB(21528);  // 24MB ..45576
    short* scaler = (short*)KB(46104);  // 4MB
    short* t1     = (short*)KB(50200);  // 8MB (Vbf/Hres dead)
    float* sbuf   = (float*)KB(58392);  // 8MB (Vres dead after Wvo proj)

    float* outH = (float*)d_out;
    float* outV = outH + (size_t)Bc * Nseq * Dh;

    // weight transposes + converts (FACT*log2e folded into Wq/bq)
    tconv<<<dim3(64, 16), 256, 0, stream>>>(Wq, WqkvT, 512, 2048, FACT * LOG2E);
    tconv<<<dim3(64, 16), 256, 0, stream>>>(Wk, WqkvT + 2048 * 512, 512, 2048, 1.f);
    tconv<<<dim3(16, 16), 256, 0, stream>>>(Wvs, WqkvT + 4096 * 512, 512, 512, 1.f);
    tconv<<<dim3(16, 16), 256, 0, stream>>>(Wvv, WvvT, 512, 512, 1.f);
    tconv<<<dim3(16, 16), 256, 0, stream>>>(Wo, WoT, 512, 512, 1.f);
    tconv<<<dim3(16, 16), 256, 0, stream>>>(Wvo, WvoT, 512, 512, 1.f);
    tconv<<<dim3(32, 16), 256, 0, stream>>>(Wlv, WlvT, 512, 1024, 1.f);
    tconv<<<dim3(64, 32), 256, 0, stream>>>(W1, W1T, 1024, 2048, 1.f);
    tconv<<<dim3(32, 64), 256, 0, stream>>>(W2, W2T, 2048, 1024, 1.f);
    bprep<<<18, 256, 0, stream>>>(bq, bk, bvs, bqkv);
    convk<<<3072, 256, 0, stream>>>(V, Vbf);
    maskprep<<<8, 256, 0, stream>>>(mask, maskadd);

    // LN1 -> bf16
    ln_kernel<short><<<2048, 256, 0, stream>>>(H, ln1g, ln1b, Hn);
    // merged QKV projection (bf16 out): Hqkv[2048][4608]
    gemm_bf16<<<dim3(36, 16, 1), 256, 0, stream>>>(Hn, 512, 0, WqkvT, 512, 0, Hqkv, 4608, 0,
                                                   bqkv, nullptr, 0, 0, 512, 2);
    gemm_bf16<<<dim3(4, 48, 1), 256, 0, stream>>>(Vbf, 512, 0, WvvT, 512, 0, VvR, 512, 0,
                                                  nullptr, nullptr, 0, 0, 512, 2);
    vattn_t<<<16384, 256, 0, stream>>>(Hqkv + 4096, 4608, VvR, VaT);

    // fused flash attention: 512 blocks x 256 threads, QBLK=64
    flash_attn<<<dim3(512), 256, 0, stream>>>(Hqkv, Hqkv + 2048, VaT, rbf, Dm, maskadd,
                                              Hres, Vres, 4608);

    // output projections with residuals (f32 into d_out)
    gemm_bf16<<<dim3(4, 16, 1), 256, 0, stream>>>(Hres, 512, 0, WoT, 512, 0, outH, 512, 0,
                                                  bo, H, 512, 0, 512, 0);
    gemm_bf16<<<dim3(4, 48, 1), 256, 0, stream>>>(Vres, 512, 0, WvoT, 512, 0, outV, 512, 0,
                                                  nullptr, V, 512, 0, 512, 0);
    convk<<<3072, 256, 0, stream>>>(outV, Vbf2);
    ln_kernel<float><<<2048, 256, 0, stream>>>(outH, ln2g, ln2b, Hn2);
    gemm_bf16<<<dim3(8, 48, 1), 256, 0, stream>>>(Vbf2, 512, 0, WlvT, 512, 0, Vp, 1024, 0,
                                                  nullptr, nullptr, 0, 0, 512, 0);
    scaler_k<<<4096, 256, 0, stream>>>(Hn2, Vp, scaler);
    gemm_bf16<<<dim3(16, 16, 1), 256, 0, stream>>>(scaler, 1024, 0, W1T, 1024, 0, t1, 2048, 0,
                                                   b1, nullptr, 0, 0, 1024, 3);
    gemm_bf16<<<dim3(8, 16, 1), 256, 0, stream>>>(t1, 2048, 0, W2T, 2048, 0, sbuf, 1024, 0,
                                                  b2, nullptr, 0, 0, 2048, 0);
    final_k<<<4096, 256, 0, stream>>>(outH, outV, sbuf, Vp);
}